// Round 1
// baseline (75.432 us; speedup 1.0000x reference)
//
#include <hip/hip_runtime.h>
#include <math.h>

#define HW (2048*2048)

// ---------------- parameter/coefficient kernel ----------------
// For each of the 10 curves (3 from L, 3 from R, 4 from S), with C = exp(P):
//   slope[i] = C[i+1]-C[i]  (15)
//   s = slope[0..13]
//   A = C[0] - sum_i i*s[i];  B = 15 * sum_i s[i]
//   ssd_k = sum_{i=0..13} (slope[i+1]-slope[i])^2
// scale(x) = A + B*x  (exactly the reference's C[0] + x*steps*sum(s) - dot(s,idx))
__global__ __launch_bounds__(64) void coeff_kernel(
    const float* __restrict__ L, const float* __restrict__ R,
    const float* __restrict__ S,
    float* __restrict__ ws, float* __restrict__ out_ssd)
{
    __shared__ float ssd_sh[10];
    int k = threadIdx.x;
    if (k < 10) {
        const float* p = (k < 3) ? (L + k*16) : (k < 6) ? (R + (k-3)*16) : (S + (k-6)*16);
        float C[16];
        #pragma unroll
        for (int i = 0; i < 16; ++i) C[i] = expf(p[i]);
        float slope[15];
        #pragma unroll
        for (int i = 0; i < 15; ++i) slope[i] = C[i+1] - C[i];
        float ssd = 0.0f, sum_s = 0.0f, dot = 0.0f;
        #pragma unroll
        for (int i = 0; i < 14; ++i) {
            float d = slope[i+1] - slope[i];
            ssd += d * d;
            sum_s += slope[i];
            dot += slope[i] * (float)i;
        }
        ws[k]      = C[0] - dot;     // A
        ws[10 + k] = 15.0f * sum_s;  // B
        ssd_sh[k]  = ssd;
    }
    __syncthreads();
    if (k == 0) {
        float t = 0.0f;
        #pragma unroll
        for (int i = 0; i < 10; ++i) t += ssd_sh[i];
        *out_ssd = t;
    }
}

// ---------------- per-pixel helpers ----------------
__device__ __forceinline__ float nan0f(float v) { return (v != v) ? 0.0f : v; }
__device__ __forceinline__ float clip01(float v) { return fminf(fmaxf(v, 0.0f), 1.0f); }
__device__ __forceinline__ float clip060(float v) { return fminf(fmaxf(v, 0.0f), 60.0f); }

// jnp.mod(a, 360): fmod, then fix sign to match divisor (positive)
__device__ __forceinline__ float jmod360(float a) {
    float t = fmodf(a, 360.0f);
    if (t < 0.0f) t += 360.0f;
    return t;
}

__device__ __forceinline__ float finv_lab(float f) {
    const float eps  = 0.20689655172413793f;  // 6/29
    const float kap  = 0.12841854934601665f;  // 3*eps^2
    const float c429 = 0.13793103448275862f;  // 4/29
    if (f <= eps) return kap * (f - c429);
    float m = fmaxf(f, 1e-4f);
    return m * m * m;
}

__device__ __forceinline__ float gamma_srgb(float v) {
    if (v <= 0.0031308f) return v * 12.92f;
    return powf(fmaxf(v, 1e-4f), 0.41666666666666669f) * 1.055f - 0.055f;
}

__device__ __forceinline__ void process_pixel(
    float x0, float x1, float x2,
    const float* __restrict__ A, const float* __restrict__ B,
    float& o0, float& o1, float& o2)
{
    // ---- adjust_3 with L coeffs (0..2); clip ALL channels after each curve ----
    x0 = x0 * (A[0] + x0 * B[0]);
    x0 = clip01(x0); x1 = clip01(x1); x2 = clip01(x2);
    x1 = x1 * (A[1] + x1 * B[1]);
    x0 = clip01(x0); x1 = clip01(x1); x2 = clip01(x2);
    x2 = x2 * (A[2] + x2 * B[2]);
    x0 = clip01(x0); x1 = clip01(x1); x2 = clip01(x2);
    x0 = nan0f(x0); x1 = nan0f(x1); x2 = nan0f(x2);

    // ---- lab_to_rgb ----
    {
        float Lv = x0 * 100.0f;
        float av = (x1 * 2.0f - 1.0f) * 110.0f;
        float bv = (x2 * 2.0f - 1.0f) * 110.0f;
        float fy = (Lv + 16.0f) * (1.0f / 116.0f);
        float fx = fy + av * (1.0f / 500.0f);
        float fz = fy - bv * (1.0f / 200.0f);
        float X = finv_lab(fx) * 0.950456f;
        float Y = finv_lab(fy);
        float Z = finv_lab(fz) * 1.088754f;
        float r =  3.2404542f * X - 1.5371385f * Y - 0.4985314f * Z;
        float g = -0.969266f  * X + 1.8760108f * Y + 0.041556f  * Z;
        float b =  0.0556434f * X - 0.2040259f * Y + 1.0572252f * Z;
        x0 = nan0f(gamma_srgb(r));
        x1 = nan0f(gamma_srgb(g));
        x2 = nan0f(gamma_srgb(b));
    }

    // ---- adjust_3 with R coeffs (3..5) ----
    // note: curve 0's scale uses the UNclipped x0 from lab_to_rgb
    x0 = x0 * (A[3] + x0 * B[3]);
    x0 = clip01(x0); x1 = clip01(x1); x2 = clip01(x2);
    x1 = x1 * (A[4] + x1 * B[4]);
    x0 = clip01(x0); x1 = clip01(x1); x2 = clip01(x2);
    x2 = x2 * (A[5] + x2 * B[5]);
    x0 = clip01(x0); x1 = clip01(x1); x2 = clip01(x2);
    x0 = nan0f(x0); x1 = nan0f(x1); x2 = nan0f(x2);

    // ---- rgb_to_hsv ----
    float h, s, v;
    {
        float r = fminf(fmaxf(x0, 1e-9f), 1.0f);
        float g = fminf(fmaxf(x1, 1e-9f), 1.0f);
        float b = fminf(fmaxf(x2, 1e-9f), 1.0f);
        float mx = fmaxf(r, fmaxf(g, b));
        float mn = fminf(r, fminf(g, b));
        float df = mx - mn + 1e-10f;
        h = 0.0f;
        if (b == mx) h = jmod360(60.0f * (r - g) / df + 240.0f);
        if (g == mx) h = jmod360(60.0f * (b - r) / df + 120.0f);
        if (r == mx) h = jmod360(60.0f * (g - b) / df);
        if (mn == mx) h = 0.0f;
        h = h / 360.0f;
        s = df / mx;
        v = mx;
        h = nan0f(h); s = nan0f(s); v = nan0f(v);
    }

    // ---- adjust_hsv with S coeffs (6..9): (0,0),(0,1),(1,1),(2,2) ----
    h = h * (A[6] + h * B[6]);
    h = clip01(h); s = clip01(s); v = clip01(v);
    s = s * (A[7] + h * B[7]);           // cin=0 (post-curve-0 h)
    h = clip01(h); s = clip01(s); v = clip01(v);
    s = s * (A[8] + s * B[8]);
    h = clip01(h); s = clip01(s); v = clip01(v);
    v = v * (A[9] + v * B[9]);
    h = clip01(h); s = clip01(s); v = clip01(v);
    h = nan0f(h); s = nan0f(s); v = nan0f(v);

    // ---- hsv_to_rgb ----
    {
        h = clip01(h); s = clip01(s); v = clip01(v);
        float c  = v * s / 60.0f;
        float hd = h * 360.0f;
        float r = v - clip060(hd - 60.0f)  * c + clip060(hd - 240.0f) * c;
        float g = v * (1.0f - s) + clip060(hd)          * c - clip060(hd - 180.0f) * c;
        float b = v * (1.0f - s) + clip060(hd - 120.0f) * c - clip060(hd - 300.0f) * c;
        o0 = clip01(nan0f(r));
        o1 = clip01(nan0f(g));
        o2 = clip01(nan0f(b));
    }
}

// ---------------- main per-pixel kernel (4 pixels/thread, float4) ----------------
__global__ __launch_bounds__(256) void pix_kernel(
    const float* __restrict__ img, const float* __restrict__ coef,
    float* __restrict__ out)
{
    __shared__ float sA[10], sB[10];
    int t = threadIdx.x;
    if (t < 10) { sA[t] = coef[t]; sB[t] = coef[10 + t]; }
    __syncthreads();

    size_t i4 = ((size_t)blockIdx.x * 256 + t) * 4;
    if (i4 + 3 >= (size_t)3 * HW) { /* only valid range launched; guard anyway */ }
    if (i4 >= (size_t)HW) return;

    float4 c0 = *(const float4*)(img + i4);
    float4 c1 = *(const float4*)(img + (size_t)HW + i4);
    float4 c2 = *(const float4*)(img + (size_t)2 * HW + i4);

    float4 o0, o1, o2;
    process_pixel(c0.x, c1.x, c2.x, sA, sB, o0.x, o1.x, o2.x);
    process_pixel(c0.y, c1.y, c2.y, sA, sB, o0.y, o1.y, o2.y);
    process_pixel(c0.z, c1.z, c2.z, sA, sB, o0.z, o1.z, o2.z);
    process_pixel(c0.w, c1.w, c2.w, sA, sB, o0.w, o1.w, o2.w);

    *(float4*)(out + i4)                    = o0;
    *(float4*)(out + (size_t)HW + i4)       = o1;
    *(float4*)(out + (size_t)2 * HW + i4)   = o2;
}

extern "C" void kernel_launch(void* const* d_in, const int* in_sizes, int n_in,
                              void* d_out, int out_size, void* d_ws, size_t ws_size,
                              hipStream_t stream)
{
    const float* img = (const float*)d_in[0];
    const float* L   = (const float*)d_in[1];
    const float* R   = (const float*)d_in[2];
    const float* S   = (const float*)d_in[3];
    float* out = (float*)d_out;
    float* ws  = (float*)d_ws;

    // 1) curve coefficients + ssd scalar (output 1 at out[3*HW])
    hipLaunchKernelGGL(coeff_kernel, dim3(1), dim3(64), 0, stream,
                       L, R, S, ws, out + (size_t)3 * HW);

    // 2) per-pixel transform: HW/4 threads, 256/block
    const int blocks = HW / (256 * 4);  // 4096
    hipLaunchKernelGGL(pix_kernel, dim3(blocks), dim3(256), 0, stream,
                       img, ws, out);
}

// Round 2
// 31.553 us; speedup vs baseline: 2.3907x; 2.3907x over previous
//
#include <hip/hip_runtime.h>
#include <math.h>

#define HW (2048*2048)

// ---------------- parameter/coefficient kernel ----------------
// For each of the 10 curves (3 from L, 3 from R, 4 from S), with C = exp(P):
//   slope[i] = C[i+1]-C[i]  (15); s = slope[0..13]
//   A = C[0] - sum_i i*s[i];  B = 15 * sum_i s[i]
//   ssd_k = sum_{i=0..13} (slope[i+1]-slope[i])^2
// scale(x) = A + B*x
__global__ __launch_bounds__(64) void coeff_kernel(
    const float* __restrict__ L, const float* __restrict__ R,
    const float* __restrict__ S,
    float* __restrict__ ws, float* __restrict__ out_ssd)
{
    __shared__ float ssd_sh[10];
    int k = threadIdx.x;
    if (k < 10) {
        const float* p = (k < 3) ? (L + k*16) : (k < 6) ? (R + (k-3)*16) : (S + (k-6)*16);
        float C[16];
        #pragma unroll
        for (int i = 0; i < 16; ++i) C[i] = expf(p[i]);
        float slope[15];
        #pragma unroll
        for (int i = 0; i < 15; ++i) slope[i] = C[i+1] - C[i];
        float ssd = 0.0f, sum_s = 0.0f, dot = 0.0f;
        #pragma unroll
        for (int i = 0; i < 14; ++i) {
            float d = slope[i+1] - slope[i];
            ssd += d * d;
            sum_s += slope[i];
            dot += slope[i] * (float)i;
        }
        ws[k]      = C[0] - dot;     // A
        ws[10 + k] = 15.0f * sum_s;  // B
        ssd_sh[k]  = ssd;
    }
    __syncthreads();
    if (k == 0) {
        float t = 0.0f;
        #pragma unroll
        for (int i = 0; i < 10; ++i) t += ssd_sh[i];
        *out_ssd = t;
    }
}

// ---------------- per-pixel helpers ----------------
__device__ __forceinline__ float nan0f(float v) { return (v != v) ? 0.0f : v; }
__device__ __forceinline__ float clip01(float v) { return fminf(fmaxf(v, 0.0f), 1.0f); }
__device__ __forceinline__ float clip060(float v) { return fminf(fmaxf(v, 0.0f), 60.0f); }
__device__ __forceinline__ float frcp(float v) { return __builtin_amdgcn_rcpf(v); }

__device__ __forceinline__ float finv_lab(float f) {
    const float eps  = 0.20689655172413793f;  // 6/29
    const float kap  = 0.12841854934601665f;  // 3*eps^2
    const float c429 = 0.13793103448275862f;  // 4/29
    float m = fmaxf(f, 1e-4f);
    float cube = m * m * m;
    float lin  = kap * (f - c429);
    return (f <= eps) ? lin : cube;
}

// x^(1/2.4) via hardware log2/exp2 (~1 ulp); input >= 1e-4
__device__ __forceinline__ float gamma_srgb(float v) {
    float p = __builtin_amdgcn_exp2f(0.41666666666666669f *
                                     __builtin_amdgcn_logf(fmaxf(v, 1e-4f)));
    return (v <= 0.0031308f) ? (v * 12.92f) : (p * 1.055f - 0.055f);
}

__device__ __forceinline__ void process_pixel(
    float x0, float x1, float x2,
    const float* __restrict__ A, const float* __restrict__ B,
    float& o0, float& o1, float& o2)
{
    // ---- adjust_3 with L coeffs (0..2); clip ALL channels after each curve ----
    x0 = x0 * (A[0] + x0 * B[0]);
    x0 = clip01(x0); x1 = clip01(x1); x2 = clip01(x2);
    x1 = x1 * (A[1] + x1 * B[1]);
    x0 = clip01(x0); x1 = clip01(x1);
    x2 = x2 * (A[2] + x2 * B[2]);
    x2 = clip01(x2);
    x0 = nan0f(x0); x1 = nan0f(x1); x2 = nan0f(x2);

    // ---- lab_to_rgb ----
    {
        float Lv = x0 * 100.0f;
        float av = (x1 * 2.0f - 1.0f) * 110.0f;
        float bv = (x2 * 2.0f - 1.0f) * 110.0f;
        float fy = (Lv + 16.0f) * (1.0f / 116.0f);
        float fx = fy + av * (1.0f / 500.0f);
        float fz = fy - bv * (1.0f / 200.0f);
        float X = finv_lab(fx) * 0.950456f;
        float Y = finv_lab(fy);
        float Z = finv_lab(fz) * 1.088754f;
        float r =  3.2404542f * X - 1.5371385f * Y - 0.4985314f * Z;
        float g = -0.969266f  * X + 1.8760108f * Y + 0.041556f  * Z;
        float b =  0.0556434f * X - 0.2040259f * Y + 1.0572252f * Z;
        x0 = nan0f(gamma_srgb(r));
        x1 = nan0f(gamma_srgb(g));
        x2 = nan0f(gamma_srgb(b));
    }

    // ---- adjust_3 with R coeffs (3..5) ----
    x0 = x0 * (A[3] + x0 * B[3]);
    x0 = clip01(x0); x1 = clip01(x1); x2 = clip01(x2);
    x1 = x1 * (A[4] + x1 * B[4]);
    x1 = clip01(x1);
    x2 = x2 * (A[5] + x2 * B[5]);
    x2 = clip01(x2);
    x0 = nan0f(x0); x1 = nan0f(x1); x2 = nan0f(x2);

    // ---- rgb_to_hsv ----
    // Mod-360 args are bounded: |60*(x-y)/df| < 60 since |x-y| <= mx-mn < df.
    //   b==mx: 60(r-g)/df+240 in [180,300]  -> mod is identity
    //   g==mx: 60(b-r)/df+120 in [ 60,180]  -> mod is identity
    //   r==mx: 60(g-b)/df     in (-60, 60)  -> +360 iff negative
    float h, s, v;
    {
        float r = fminf(fmaxf(x0, 1e-9f), 1.0f);
        float g = fminf(fmaxf(x1, 1e-9f), 1.0f);
        float b = fminf(fmaxf(x2, 1e-9f), 1.0f);
        float mx = fmaxf(r, fmaxf(g, b));
        float mn = fminf(r, fminf(g, b));
        float df = mx - mn + 1e-10f;
        float inv_df = frcp(df);
        float hb = (60.0f * (r - g)) * inv_df + 240.0f;
        float hg = (60.0f * (b - r)) * inv_df + 120.0f;
        float hr = (60.0f * (g - b)) * inv_df;
        if (hr < 0.0f) hr += 360.0f;
        h = 0.0f;
        if (b == mx) h = hb;
        if (g == mx) h = hg;
        if (r == mx) h = hr;
        if (mn == mx) h = 0.0f;
        h = h * (1.0f / 360.0f);
        s = df * frcp(mx);
        v = mx;
        h = nan0f(h); s = nan0f(s); v = nan0f(v);
    }

    // ---- adjust_hsv with S coeffs (6..9): (0,0),(0,1),(1,1),(2,2) ----
    h = h * (A[6] + h * B[6]);
    h = clip01(h); s = clip01(s); v = clip01(v);
    s = s * (A[7] + h * B[7]);           // cin=0 (post-curve-0 h)
    s = clip01(s);
    s = s * (A[8] + s * B[8]);
    s = clip01(s);
    v = v * (A[9] + v * B[9]);
    v = clip01(v);
    h = nan0f(h); s = nan0f(s); v = nan0f(v);

    // ---- hsv_to_rgb ----
    {
        float c  = v * s * (1.0f / 60.0f);
        float hd = h * 360.0f;
        float vs = v * (1.0f - s);
        float r = v - clip060(hd - 60.0f)  * c + clip060(hd - 240.0f) * c;
        float g = vs + clip060(hd)          * c - clip060(hd - 180.0f) * c;
        float b = vs + clip060(hd - 120.0f) * c - clip060(hd - 300.0f) * c;
        o0 = clip01(nan0f(r));
        o1 = clip01(nan0f(g));
        o2 = clip01(nan0f(b));
    }
}

// ---------------- main per-pixel kernel (4 pixels/thread, float4) ----------------
__global__ __launch_bounds__(256) void pix_kernel(
    const float* __restrict__ img, const float* __restrict__ coef,
    float* __restrict__ out)
{
    __shared__ float sA[10], sB[10];
    int t = threadIdx.x;
    if (t < 10) { sA[t] = coef[t]; sB[t] = coef[10 + t]; }
    __syncthreads();

    size_t i4 = ((size_t)blockIdx.x * 256 + t) * 4;
    if (i4 >= (size_t)HW) return;

    float4 c0 = *(const float4*)(img + i4);
    float4 c1 = *(const float4*)(img + (size_t)HW + i4);
    float4 c2 = *(const float4*)(img + (size_t)2 * HW + i4);

    float4 o0, o1, o2;
    process_pixel(c0.x, c1.x, c2.x, sA, sB, o0.x, o1.x, o2.x);
    process_pixel(c0.y, c1.y, c2.y, sA, sB, o0.y, o1.y, o2.y);
    process_pixel(c0.z, c1.z, c2.z, sA, sB, o0.z, o1.z, o2.z);
    process_pixel(c0.w, c1.w, c2.w, sA, sB, o0.w, o1.w, o2.w);

    *(float4*)(out + i4)                    = o0;
    *(float4*)(out + (size_t)HW + i4)       = o1;
    *(float4*)(out + (size_t)2 * HW + i4)   = o2;
}

extern "C" void kernel_launch(void* const* d_in, const int* in_sizes, int n_in,
                              void* d_out, int out_size, void* d_ws, size_t ws_size,
                              hipStream_t stream)
{
    const float* img = (const float*)d_in[0];
    const float* L   = (const float*)d_in[1];
    const float* R   = (const float*)d_in[2];
    const float* S   = (const float*)d_in[3];
    float* out = (float*)d_out;
    float* ws  = (float*)d_ws;

    // 1) curve coefficients + ssd scalar (output 1 at out[3*HW])
    hipLaunchKernelGGL(coeff_kernel, dim3(1), dim3(64), 0, stream,
                       L, R, S, ws, out + (size_t)3 * HW);

    // 2) per-pixel transform: HW/4 threads, 256/block
    const int blocks = HW / (256 * 4);  // 4096
    hipLaunchKernelGGL(pix_kernel, dim3(blocks), dim3(256), 0, stream,
                       img, ws, out);
}

// Round 5
// 26.929 us; speedup vs baseline: 2.8012x; 1.1717x over previous
//
#include <hip/hip_runtime.h>
#include <math.h>

#define HW (2048*2048)

typedef float fvec4 __attribute__((ext_vector_type(4)));

// ---------------- helpers ----------------
__device__ __forceinline__ float clip01(float v) { return fminf(fmaxf(v, 0.0f), 1.0f); }
__device__ __forceinline__ float clip060(float v) { return fminf(fmaxf(v, 0.0f), 60.0f); }
__device__ __forceinline__ float frcp(float v)   { return __builtin_amdgcn_rcpf(v); }
__device__ __forceinline__ float fexp(float x)   { return __builtin_amdgcn_exp2f(x * 1.4426950408889634f); }

__device__ __forceinline__ float finv_lab(float f) {
    const float eps  = 0.20689655172413793f;  // 6/29
    const float kap  = 0.12841854934601665f;  // 3*eps^2
    const float c429 = 0.13793103448275862f;  // 4/29
    float m = fmaxf(f, 1e-4f);
    float cube = m * m * m;
    float lin  = kap * (f - c429);
    return (f <= eps) ? lin : cube;
}

// x^(1/2.4) via hardware log2/exp2 (~1 ulp); arg clamped >= 1e-4
__device__ __forceinline__ float gamma_srgb(float v) {
    float p = __builtin_amdgcn_exp2f(0.41666666666666669f *
                                     __builtin_amdgcn_logf(fmaxf(v, 1e-4f)));
    return (v <= 0.0031308f) ? (v * 12.92f) : (p * 1.055f - 0.055f);
}

// NOTE: all nan0f() from the reference are provably dead here: every
// intermediate is finite (inputs in [0,1], rcp(df) <= 1e10, log arg >= 1e-4),
// so NaN can never be produced.
__device__ __forceinline__ void process_pixel(
    float x0, float x1, float x2,
    const float* __restrict__ A, const float* __restrict__ B,
    float& o0, float& o1, float& o2)
{
    // ---- adjust_3 with L coeffs (0..2); clip ALL channels after each curve ----
    x0 = x0 * (A[0] + x0 * B[0]);
    x0 = clip01(x0); x1 = clip01(x1); x2 = clip01(x2);
    x1 = x1 * (A[1] + x1 * B[1]);
    x1 = clip01(x1);
    x2 = x2 * (A[2] + x2 * B[2]);
    x2 = clip01(x2);

    // ---- lab_to_rgb ----
    {
        float Lv = x0 * 100.0f;
        float av = (x1 * 2.0f - 1.0f) * 110.0f;
        float bv = (x2 * 2.0f - 1.0f) * 110.0f;
        float fy = (Lv + 16.0f) * (1.0f / 116.0f);
        float fx = fy + av * (1.0f / 500.0f);
        float fz = fy - bv * (1.0f / 200.0f);
        float X = finv_lab(fx) * 0.950456f;
        float Y = finv_lab(fy);
        float Z = finv_lab(fz) * 1.088754f;
        float r =  3.2404542f * X - 1.5371385f * Y - 0.4985314f * Z;
        float g = -0.969266f  * X + 1.8760108f * Y + 0.041556f  * Z;
        float b =  0.0556434f * X - 0.2040259f * Y + 1.0572252f * Z;
        x0 = gamma_srgb(r);
        x1 = gamma_srgb(g);
        x2 = gamma_srgb(b);
    }

    // ---- adjust_3 with R coeffs (3..5) ----
    // curve 0's scale uses the UNclipped x0 from lab_to_rgb (matches reference)
    x0 = x0 * (A[3] + x0 * B[3]);
    x0 = clip01(x0); x1 = clip01(x1); x2 = clip01(x2);
    x1 = x1 * (A[4] + x1 * B[4]);
    x1 = clip01(x1);
    x2 = x2 * (A[5] + x2 * B[5]);
    x2 = clip01(x2);

    // ---- rgb_to_hsv ----
    // inputs already in [0,1] -> only the lower clamp (1e-9) is live.
    // Mod-360 args are bounded: |60*(x-y)/df| < 60 since |x-y| <= mx-mn < df.
    //   b==mx: +240 -> [180,300] identity; g==mx: +120 -> [60,180] identity;
    //   r==mx: (-60,60) -> +360 iff negative.
    float h, s, v;
    {
        float r = fmaxf(x0, 1e-9f);
        float g = fmaxf(x1, 1e-9f);
        float b = fmaxf(x2, 1e-9f);
        float mx = fmaxf(r, fmaxf(g, b));
        float mn = fminf(r, fminf(g, b));
        float df = mx - mn + 1e-10f;
        float inv_df = frcp(df);
        float hb = (60.0f * (r - g)) * inv_df + 240.0f;
        float hg = (60.0f * (b - r)) * inv_df + 120.0f;
        float hr = (60.0f * (g - b)) * inv_df;
        if (hr < 0.0f) hr += 360.0f;
        h = 0.0f;
        if (b == mx) h = hb;
        if (g == mx) h = hg;
        if (r == mx) h = hr;
        if (mn == mx) h = 0.0f;
        h = h * (1.0f / 360.0f);
        s = df * frcp(mx);
        v = mx;
    }

    // ---- adjust_hsv with S coeffs (6..9): (0,0),(0,1),(1,1),(2,2) ----
    h = h * (A[6] + h * B[6]);
    h = clip01(h); s = clip01(s); v = clip01(v);
    s = s * (A[7] + h * B[7]);           // cin=0 (post-curve-0 h)
    s = clip01(s);
    s = s * (A[8] + s * B[8]);
    s = clip01(s);
    v = v * (A[9] + v * B[9]);
    v = clip01(v);

    // ---- hsv_to_rgb (inputs already in [0,1]) ----
    {
        float c  = v * s * (1.0f / 60.0f);
        float hd = h * 360.0f;
        float vs = v * (1.0f - s);
        float r = v  - clip060(hd - 60.0f)  * c + clip060(hd - 240.0f) * c;
        float g = vs + clip060(hd)          * c - clip060(hd - 180.0f) * c;
        float b = vs + clip060(hd - 120.0f) * c - clip060(hd - 300.0f) * c;
        o0 = clip01(r);
        o1 = clip01(g);
        o2 = clip01(b);
    }
}

// ---------------- fused kernel: per-block coeff recompute + per-pixel map ----------------
// Each block recomputes the 10 curves' (A,B) in lanes 0..9 (deterministic,
// identical across blocks; ~200 cycles hidden under occupancy). Block 0 also
// writes the ssd scalar. This removes the separate serial coeff launch.
__global__ __launch_bounds__(256) void pix_kernel(
    const float* __restrict__ img,
    const float* __restrict__ L, const float* __restrict__ R,
    const float* __restrict__ S,
    float* __restrict__ out)
{
    __shared__ float sA[10], sB[10], sSSD[10];
    int t = threadIdx.x;
    if (t < 10) {
        const float* p = (t < 3) ? (L + t*16) : (t < 6) ? (R + (t-3)*16) : (S + (t-6)*16);
        float C[16];
        #pragma unroll
        for (int i = 0; i < 16; ++i) C[i] = fexp(p[i]);
        float slope[15];
        #pragma unroll
        for (int i = 0; i < 15; ++i) slope[i] = C[i+1] - C[i];
        float ssd = 0.0f, sum_s = 0.0f, dot = 0.0f;
        #pragma unroll
        for (int i = 0; i < 14; ++i) {
            float d = slope[i+1] - slope[i];
            ssd += d * d;
            sum_s += slope[i];
            dot += slope[i] * (float)i;
        }
        sA[t]   = C[0] - dot;
        sB[t]   = 15.0f * sum_s;
        sSSD[t] = ssd;
    }
    __syncthreads();

    if (blockIdx.x == 0 && t == 0) {
        float tot = 0.0f;
        #pragma unroll
        for (int i = 0; i < 10; ++i) tot += sSSD[i];
        out[(size_t)3 * HW] = tot;
    }

    size_t i4 = ((size_t)blockIdx.x * 256 + t) * 4;
    if (i4 >= (size_t)HW) return;

    fvec4 c0 = *(const fvec4*)(img + i4);
    fvec4 c1 = *(const fvec4*)(img + (size_t)HW + i4);
    fvec4 c2 = *(const fvec4*)(img + (size_t)2 * HW + i4);

    fvec4 o0, o1, o2;
    float a0, a1, a2;
    process_pixel(c0.x, c1.x, c2.x, sA, sB, a0, a1, a2); o0.x = a0; o1.x = a1; o2.x = a2;
    process_pixel(c0.y, c1.y, c2.y, sA, sB, a0, a1, a2); o0.y = a0; o1.y = a1; o2.y = a2;
    process_pixel(c0.z, c1.z, c2.z, sA, sB, a0, a1, a2); o0.z = a0; o1.z = a1; o2.z = a2;
    process_pixel(c0.w, c1.w, c2.w, sA, sB, a0, a1, a2); o0.w = a0; o1.w = a1; o2.w = a2;

    // streamed output, never re-read -> non-temporal
    __builtin_nontemporal_store(o0, (fvec4*)(out + i4));
    __builtin_nontemporal_store(o1, (fvec4*)(out + (size_t)HW + i4));
    __builtin_nontemporal_store(o2, (fvec4*)(out + (size_t)2 * HW + i4));
}

extern "C" void kernel_launch(void* const* d_in, const int* in_sizes, int n_in,
                              void* d_out, int out_size, void* d_ws, size_t ws_size,
                              hipStream_t stream)
{
    const float* img = (const float*)d_in[0];
    const float* L   = (const float*)d_in[1];
    const float* R   = (const float*)d_in[2];
    const float* S   = (const float*)d_in[3];
    float* out = (float*)d_out;

    const int blocks = HW / (256 * 4);  // 4096
    hipLaunchKernelGGL(pix_kernel, dim3(blocks), dim3(256), 0, stream,
                       img, L, R, S, out);
}

// Round 6
// 22.785 us; speedup vs baseline: 3.3106x; 1.1819x over previous
//
#include <hip/hip_runtime.h>
#include <math.h>

#define HW (2048*2048)

typedef float fvec4 __attribute__((ext_vector_type(4)));

// ---------------- helpers ----------------
__device__ __forceinline__ float med3(float v, float lo, float hi) {
    return __builtin_amdgcn_fmed3f(v, lo, hi);
}
__device__ __forceinline__ float clip01(float v)  { return med3(v, 0.0f, 1.0f); }
__device__ __forceinline__ float clip060(float v) { return med3(v, 0.0f, 60.0f); }
__device__ __forceinline__ float frcp(float v)    { return __builtin_amdgcn_rcpf(v); }
__device__ __forceinline__ float fexp(float x)    { return __builtin_amdgcn_exp2f(x * 1.4426950408889634f); }

__device__ __forceinline__ float finv_lab(float f) {
    const float eps  = 0.20689655172413793f;  // 6/29
    const float kap  = 0.12841854934601665f;  // 3*eps^2
    const float c429 = 0.13793103448275862f;  // 4/29
    float m = fmaxf(f, 1e-4f);
    float cube = m * m * m;
    float lin  = kap * (f - c429);
    return (f <= eps) ? lin : cube;
}

// x^(1/2.4) via hardware log2/exp2 (~1 ulp); arg clamped >= 1e-4
__device__ __forceinline__ float gamma_srgb(float v) {
    float p = __builtin_amdgcn_exp2f(0.41666666666666669f *
                                     __builtin_amdgcn_logf(fmaxf(v, 1e-4f)));
    return (v <= 0.0031308f) ? (v * 12.92f) : (p * 1.055f - 0.055f);
}

// NOTE: all nan0f() from the reference are provably dead (every intermediate
// finite), and the reference's (mn==mx -> h=0) override is dead too: mn==mx
// implies all channels equal, so r==mx wins the chain and hr = 60*0*inv = 0.
__device__ __forceinline__ void process_pixel(
    float x0, float x1, float x2,
    const float A[10], const float B[10],
    float& o0, float& o1, float& o2)
{
    // ---- adjust_3 with L coeffs (0..2); clip ALL channels after each curve ----
    x0 = x0 * (A[0] + x0 * B[0]);
    x0 = clip01(x0); x1 = clip01(x1); x2 = clip01(x2);
    x1 = x1 * (A[1] + x1 * B[1]);
    x1 = clip01(x1);
    x2 = x2 * (A[2] + x2 * B[2]);
    x2 = clip01(x2);

    // ---- lab_to_rgb (white point folded into M2 columns at compile time) ----
    {
        float fy = x0 * (100.0f / 116.0f) + (16.0f / 116.0f);
        float fx = fy + (x1 * 2.0f - 1.0f) * (110.0f / 500.0f);
        float fz = fy - (x2 * 2.0f - 1.0f) * (110.0f / 200.0f);
        float X = finv_lab(fx);
        float Y = finv_lab(fy);
        float Z = finv_lab(fz);
        float r = (3.2404542f * 0.950456f) * X + (-1.5371385f) * Y + (-0.4985314f * 1.088754f) * Z;
        float g = (-0.969266f * 0.950456f) * X + (1.8760108f)  * Y + (0.041556f  * 1.088754f) * Z;
        float b = (0.0556434f * 0.950456f) * X + (-0.2040259f) * Y + (1.0572252f * 1.088754f) * Z;
        x0 = gamma_srgb(r);
        x1 = gamma_srgb(g);
        x2 = gamma_srgb(b);
    }

    // ---- adjust_3 with R coeffs (3..5) ----
    // curve 0's scale uses the UNclipped x0 from lab_to_rgb (matches reference)
    x0 = x0 * (A[3] + x0 * B[3]);
    x0 = clip01(x0); x1 = clip01(x1); x2 = clip01(x2);
    x1 = x1 * (A[4] + x1 * B[4]);
    x1 = clip01(x1);
    x2 = x2 * (A[5] + x2 * B[5]);
    x2 = clip01(x2);

    // ---- rgb_to_hsv ----
    // inputs in [0,1] -> only lower clamp live. Mod-360 args bounded (<60 in
    // magnitude before offsets) -> identity except hr negative wrap.
    float h, s, v;
    {
        float r = fmaxf(x0, 1e-9f);
        float g = fmaxf(x1, 1e-9f);
        float b = fmaxf(x2, 1e-9f);
        float mx = fmaxf(fmaxf(r, g), b);   // v_max3
        float mn = fminf(fminf(r, g), b);   // v_min3
        float df = mx - mn + 1e-10f;
        float inv_df = frcp(df);
        float hb = (60.0f * (r - g)) * inv_df + 240.0f;
        float hg = (60.0f * (b - r)) * inv_df + 120.0f;
        float hr = (60.0f * (g - b)) * inv_df;
        hr = (hr < 0.0f) ? hr + 360.0f : hr;
        // priority r > g > b (reference overwrites in that order)
        h = (r == mx) ? hr : ((g == mx) ? hg : hb);
        h = h * (1.0f / 360.0f);
        s = df * frcp(mx);
        v = mx;
    }

    // ---- adjust_hsv with S coeffs (6..9): (0,0),(0,1),(1,1),(2,2) ----
    h = h * (A[6] + h * B[6]);
    h = clip01(h); s = clip01(s); v = clip01(v);
    s = s * (A[7] + h * B[7]);           // cin=0 (post-curve-0 h)
    s = clip01(s);
    s = s * (A[8] + s * B[8]);
    s = clip01(s);
    v = v * (A[9] + v * B[9]);
    v = clip01(v);

    // ---- hsv_to_rgb (inputs already in [0,1]) ----
    {
        float c  = v * s * (1.0f / 60.0f);
        float hd = h * 360.0f;
        float vs = v - v * s;
        float r = v  - clip060(hd - 60.0f)  * c + clip060(hd - 240.0f) * c;
        float g = vs + clip060(hd)          * c - clip060(hd - 180.0f) * c;
        float b = vs + clip060(hd - 120.0f) * c - clip060(hd - 300.0f) * c;
        o0 = clip01(r);
        o1 = clip01(g);
        o2 = clip01(b);
    }
}

// ---------------- fused kernel: per-block coeff recompute + per-pixel map ----------------
__global__ __launch_bounds__(256) void pix_kernel(
    const float* __restrict__ img,
    const float* __restrict__ L, const float* __restrict__ R,
    const float* __restrict__ S,
    float* __restrict__ out)
{
    __shared__ float sA[10], sB[10], sSSD[10];
    int t = threadIdx.x;
    if (t < 10) {
        const float* p = (t < 3) ? (L + t*16) : (t < 6) ? (R + (t-3)*16) : (S + (t-6)*16);
        float C[16];
        #pragma unroll
        for (int i = 0; i < 16; ++i) C[i] = fexp(p[i]);
        float slope[15];
        #pragma unroll
        for (int i = 0; i < 15; ++i) slope[i] = C[i+1] - C[i];
        float ssd = 0.0f, sum_s = 0.0f, dot = 0.0f;
        #pragma unroll
        for (int i = 0; i < 14; ++i) {
            float d = slope[i+1] - slope[i];
            ssd += d * d;
            sum_s += slope[i];
            dot += slope[i] * (float)i;
        }
        sA[t]   = C[0] - dot;
        sB[t]   = 15.0f * sum_s;
        sSSD[t] = ssd;
    }
    __syncthreads();

    if (blockIdx.x == 0 && t == 0) {
        float tot = 0.0f;
        #pragma unroll
        for (int i = 0; i < 10; ++i) tot += sSSD[i];
        out[(size_t)3 * HW] = tot;
    }

    // hoist coefficients LDS -> registers ONCE (prevents per-pixel ds_read)
    float A[10], B[10];
    #pragma unroll
    for (int i = 0; i < 10; ++i) { A[i] = sA[i]; B[i] = sB[i]; }

    size_t i4 = ((size_t)blockIdx.x * 256 + t) * 4;

    fvec4 c0 = *(const fvec4*)(img + i4);
    fvec4 c1 = *(const fvec4*)(img + (size_t)HW + i4);
    fvec4 c2 = *(const fvec4*)(img + (size_t)2 * HW + i4);

    fvec4 o0, o1, o2;
    float a0, a1, a2;
    process_pixel(c0.x, c1.x, c2.x, A, B, a0, a1, a2); o0.x = a0; o1.x = a1; o2.x = a2;
    process_pixel(c0.y, c1.y, c2.y, A, B, a0, a1, a2); o0.y = a0; o1.y = a1; o2.y = a2;
    process_pixel(c0.z, c1.z, c2.z, A, B, a0, a1, a2); o0.z = a0; o1.z = a1; o2.z = a2;
    process_pixel(c0.w, c1.w, c2.w, A, B, a0, a1, a2); o0.w = a0; o1.w = a1; o2.w = a2;

    // streamed output, never re-read -> non-temporal
    __builtin_nontemporal_store(o0, (fvec4*)(out + i4));
    __builtin_nontemporal_store(o1, (fvec4*)(out + (size_t)HW + i4));
    __builtin_nontemporal_store(o2, (fvec4*)(out + (size_t)2 * HW + i4));
}

extern "C" void kernel_launch(void* const* d_in, const int* in_sizes, int n_in,
                              void* d_out, int out_size, void* d_ws, size_t ws_size,
                              hipStream_t stream)
{
    const float* img = (const float*)d_in[0];
    const float* L   = (const float*)d_in[1];
    const float* R   = (const float*)d_in[2];
    const float* S   = (const float*)d_in[3];
    float* out = (float*)d_out;

    const int blocks = HW / (256 * 4);  // 4096
    hipLaunchKernelGGL(pix_kernel, dim3(blocks), dim3(256), 0, stream,
                       img, L, R, S, out);
}